// Round 16
// baseline (154.288 us; speedup 1.0000x reference)
//
#include <hip/hip_runtime.h>
#include <hip/hip_bf16.h>

// GlobalAttention: B=4, N=2048, D=1024, A=256, f32 in/out.
// out = softmax( (X Wq + bq)(X Wk + bk)^T + mask ) X
// R16: k_pv re-tiled to BM=128 BN=128 BK=32, 3-buffer depth-2 (VMCNT(2)),
// 48KB LDS -> 2 blocks/CU resident (grid 512) — same occupancy trade that won
// for proj in R10. 8 waves 2Mx4N (wave 64x32). proj/scores/softmax/prep = R15.

#define BB 4
#define NN 2048
#define DD 1024
#define AA 256

using bf16x8 = __attribute__((ext_vector_type(8))) __bf16;
using f32x4  = __attribute__((ext_vector_type(4))) float;

#define MFMA(a, b, c) __builtin_amdgcn_mfma_f32_16x16x32_bf16(a, b, c, 0, 0, 0)

#define VMCNT(n) asm volatile("s_waitcnt vmcnt(" #n ")" ::: "memory")
#define LGKM0()  asm volatile("s_waitcnt lgkmcnt(0)" ::: "memory")
#define SB0()    __builtin_amdgcn_sched_barrier(0)
#define CFENCE() asm volatile("" ::: "memory")
#define BARRIER() __builtin_amdgcn_s_barrier()

static __device__ __forceinline__ unsigned short f2bf(float x) {
    union { float f; unsigned int u; } c; c.f = x;
    unsigned int u = c.u;
    u += 0x7fffu + ((u >> 16) & 1u);   // round-to-nearest-even
    return (unsigned short)(u >> 16);
}
static __device__ __forceinline__ float bf2f(unsigned short h) {
    union { unsigned int u; float f; } c; c.u = ((unsigned int)h) << 16;
    return c.f;
}

// ---- swizzle: slot' = slot ^ swz(row); involution on stage-src AND ds_read ----
template<int SLOTS>
static __device__ __forceinline__ int swz(int r) {
    return (SLOTS == 4) ? ((r >> 1) & 3) : (r & 7);
}

template<int ROWS, int BK, int THREADS, int I0, int I1>
static __device__ __forceinline__ void stage_part(const unsigned short* __restrict__ g,
                                                  int pitch, unsigned short* lds, int t) {
    constexpr int SLOTS = BK / 8;
#pragma unroll
    for (int i = I0; i < I1; ++i) {
        int tt = t + i * THREADS;
        int row = tt / SLOTS;
        int slot = (tt % SLOTS) ^ swz<SLOTS>(row);
        const char* src = (const char*)(g + (size_t)row * pitch) + slot * 16;
        __builtin_amdgcn_global_load_lds((const unsigned int*)src,
                                         (unsigned int*)((char*)lds + (size_t)tt * 16),
                                         16, 0, 0);
    }
}

template<int BK>
static __device__ __forceinline__ bf16x8 ldsfrag(const unsigned short* lds, int row,
                                                 int ks, int lane) {
    constexpr int SLOTS = BK / 8;
    int r = row + (lane & 15);
    int slot = (ks * 4 + (lane >> 4)) ^ swz<SLOTS>(r);
    return *reinterpret_cast<const bf16x8*>((const char*)lds + (size_t)r * (BK * 2) + slot * 16);
}

// ---------- fused prep: X -> Xh, Xl (row-major) and XT bf16 [B][D][N] ----------
__global__ __launch_bounds__(256) void k_prep(const float* __restrict__ X,
                                              unsigned short* __restrict__ Xh,
                                              unsigned short* __restrict__ Xl,
                                              unsigned short* __restrict__ XT) {
    __shared__ unsigned short tile[64][65];   // [d][n], hi values
    int t = threadIdx.x;
    int n0 = blockIdx.x * 64, d0 = blockIdx.y * 64;
    const float* Xb = X + (size_t)blockIdx.z * NN * DD;
    unsigned short* Xhb = Xh + (size_t)blockIdx.z * NN * DD;
    unsigned short* Xlb = Xl + (size_t)blockIdx.z * NN * DD;
    unsigned short* XTb = XT + (size_t)blockIdx.z * DD * NN;
    int r = t >> 4, c4 = (t & 15) * 4;
#pragma unroll
    for (int i = 0; i < 4; ++i) {
        int row = r + 16 * i;
        float4 v = *reinterpret_cast<const float4*>(Xb + (size_t)(n0 + row) * DD + d0 + c4);
        ushort4 h, l;
        h.x = f2bf(v.x); l.x = f2bf(v.x - bf2f(h.x));
        h.y = f2bf(v.y); l.y = f2bf(v.y - bf2f(h.y));
        h.z = f2bf(v.z); l.z = f2bf(v.z - bf2f(h.z));
        h.w = f2bf(v.w); l.w = f2bf(v.w - bf2f(h.w));
        *reinterpret_cast<ushort4*>(Xhb + (size_t)(n0 + row) * DD + d0 + c4) = h;
        *reinterpret_cast<ushort4*>(Xlb + (size_t)(n0 + row) * DD + d0 + c4) = l;
        tile[c4 + 0][row] = h.x;
        tile[c4 + 1][row] = h.y;
        tile[c4 + 2][row] = h.z;
        tile[c4 + 3][row] = h.w;
    }
    __syncthreads();
    int j = t & 63, i4 = t >> 6;
#pragma unroll
    for (int jj = i4; jj < 64; jj += 4)
        XTb[(size_t)(d0 + jj) * NN + n0 + j] = tile[jj][j];
}

// ---------- prep: W[D][A] -> WT hi/lo bf16 [A][D] ----------
__global__ __launch_bounds__(256) void k_wsplit(const float* __restrict__ W,
                                                unsigned short* __restrict__ WTh,
                                                unsigned short* __restrict__ WTl) {
    int idx = blockIdx.x * 256 + threadIdx.x;
    int a = idx >> 10;
    int d = idx & (DD - 1);
    float w = W[(size_t)d * AA + a];
    unsigned short hi = f2bf(w);
    WTh[idx] = hi;
    WTl[idx] = f2bf(w - bf2f(hi));
}

// ---------- fused proj: {Q,K} = X W{q,k} + b -> split bf16 [B*N][A] ----------
// 64x128 tile, 4 waves of 64x32, 3-buffer depth-2 (VMCNT(6)). grid (512).
__global__ __launch_bounds__(256) void k_proj(const unsigned short* __restrict__ Xh,
                                              const unsigned short* __restrict__ Xl,
                                              const unsigned short* __restrict__ WqTh,
                                              const unsigned short* __restrict__ WqTl,
                                              const unsigned short* __restrict__ WkTh,
                                              const unsigned short* __restrict__ WkTl,
                                              const float* __restrict__ bq,
                                              const float* __restrict__ bk,
                                              unsigned short* __restrict__ Qh,
                                              unsigned short* __restrict__ Ql,
                                              unsigned short* __restrict__ Kh,
                                              unsigned short* __restrict__ Kl) {
    extern __shared__ unsigned short dyn[];
    int t = threadIdx.x, lane = t & 63, wave = t >> 6;
    int bid = blockIdx.x;
    int xcd = bid & 7, idx = bid >> 3;        // idx 0..63
    int rowpanel = xcd * 16 + (idx >> 2);
    int yy = idx & 3;
    int row0 = rowpanel * 64;
    int which = yy >> 1;
    int col0 = (yy & 1) * 128;
    const unsigned short* BTh = which ? WkTh : WqTh;
    const unsigned short* BTl = which ? WkTl : WqTl;
    const float* bias = which ? bk : bq;
    unsigned short* Oh = which ? Kh : Qh;
    unsigned short* Ol = which ? Kl : Ql;
    const unsigned short* Abase_h = Xh + (size_t)row0 * DD;
    const unsigned short* Abase_l = Xl + (size_t)row0 * DD;
    const unsigned short* Bbase_h = BTh + (size_t)col0 * DD;
    const unsigned short* Bbase_l = BTl + (size_t)col0 * DD;
    int wc = wave * 32;
    f32x4 acc[4][2] = {};
#pragma unroll
    for (int p = 0; p < 2; ++p) {
        unsigned short* bp = dyn + p * 12288;
        int k0 = p * 32;
        stage_part<64, 32, 256, 0, 1>(Abase_h + k0, DD, bp, t);
        stage_part<64, 32, 256, 0, 1>(Abase_l + k0, DD, bp + 2048, t);
        stage_part<128, 32, 256, 0, 2>(Bbase_h + k0, DD, bp + 4096, t);
        stage_part<128, 32, 256, 0, 2>(Bbase_l + k0, DD, bp + 8192, t);
    }
    constexpr int NT = DD / 32;   // 32
    int cur = 0;
    for (int tt = 0; tt < NT; ++tt) {
        int st = (cur >= 1) ? cur - 1 : 2;          // (cur+2)%3
        CFENCE();
        if (tt == NT - 1) { VMCNT(0); } else { VMCNT(6); }
        BARRIER();
        CFENCE();
        unsigned short* bc = dyn + cur * 12288;
        if (tt + 2 < NT) {
            unsigned short* bs = dyn + st * 12288;
            int k0 = (tt + 2) * 32;
            stage_part<64, 32, 256, 0, 1>(Abase_h + k0, DD, bs, t);
            stage_part<64, 32, 256, 0, 1>(Abase_l + k0, DD, bs + 2048, t);
            stage_part<128, 32, 256, 0, 2>(Bbase_h + k0, DD, bs + 4096, t);
            stage_part<128, 32, 256, 0, 2>(Bbase_l + k0, DD, bs + 8192, t);
        }
        bf16x8 ah[4], al[4], bh[2], bl[2];
#pragma unroll
        for (int f = 0; f < 4; ++f) {
            ah[f] = ldsfrag<32>(bc, f * 16, 0, lane);
            al[f] = ldsfrag<32>(bc + 2048, f * 16, 0, lane);
        }
#pragma unroll
        for (int n = 0; n < 2; ++n) {
            bh[n] = ldsfrag<32>(bc + 4096, wc + n * 16, 0, lane);
            bl[n] = ldsfrag<32>(bc + 8192, wc + n * 16, 0, lane);
        }
        LGKM0();
        SB0();
#pragma unroll
        for (int m = 0; m < 4; ++m)
#pragma unroll
            for (int n = 0; n < 2; ++n) {
                acc[m][n] = MFMA(ah[m], bh[n], acc[m][n]);
                acc[m][n] = MFMA(ah[m], bl[n], acc[m][n]);
                acc[m][n] = MFMA(al[m], bh[n], acc[m][n]);
            }
        cur = (cur == 2) ? 0 : cur + 1;
    }
    int r4 = (lane >> 4) << 2, cl = lane & 15;
#pragma unroll
    for (int m = 0; m < 4; ++m)
#pragma unroll
        for (int n = 0; n < 2; ++n) {
            int col = col0 + wc + n * 16 + cl;
            float bv = bias[col];
#pragma unroll
            for (int r = 0; r < 4; ++r) {
                int row = row0 + m * 16 + r4 + r;
                float v = acc[m][n][r] + bv;
                unsigned short hi = f2bf(v);
                size_t o = (size_t)row * AA + col;
                Oh[o] = hi;
                Ol[o] = f2bf(v - bf2f(hi));
            }
        }
}

// ---------- scores: S[b][n][m] = sum_a Q[n][a] K[m][a]  (f32) ----------
__global__ __launch_bounds__(256) void k_scores(const unsigned short* __restrict__ Qh,
                                                const unsigned short* __restrict__ Ql,
                                                const unsigned short* __restrict__ Kh,
                                                const unsigned short* __restrict__ Kl,
                                                float* __restrict__ S) {
    __shared__ unsigned short ldsAh[2][128 * 32], ldsAl[2][128 * 32];
    __shared__ unsigned short ldsBh[2][128 * 32], ldsBl[2][128 * 32];
    int t = threadIdx.x, lane = t & 63, wave = t >> 6;
    int bid = blockIdx.x + 16 * blockIdx.y + 256 * blockIdx.z;
    int sbid = (bid & 7) * 128 + (bid >> 3);
    int b = sbid >> 8;
    int nrow0 = (sbid & 15) * 128;
    int mcol0 = ((sbid >> 4) & 15) * 128;
    const unsigned short* Qhb = Qh + (size_t)(b * NN + nrow0) * AA;
    const unsigned short* Qlb = Ql + (size_t)(b * NN + nrow0) * AA;
    const unsigned short* Khb = Kh + (size_t)(b * NN + mcol0) * AA;
    const unsigned short* Klb = Kl + (size_t)(b * NN + mcol0) * AA;
    int wr = (wave >> 1) * 64, wc = (wave & 1) * 64;
    f32x4 acc[4][4] = {};
    stage_part<128, 32, 256, 0, 2>(Qhb, AA, ldsAh[0], t);
    stage_part<128, 32, 256, 0, 2>(Qlb, AA, ldsAl[0], t);
    stage_part<128, 32, 256, 0, 2>(Khb, AA, ldsBh[0], t);
    stage_part<128, 32, 256, 0, 2>(Klb, AA, ldsBl[0], t);
    constexpr int NT = AA / 32;
    for (int tt = 0; tt < NT; ++tt) {
        int cur = tt & 1;
        CFENCE();
        VMCNT(0);
        BARRIER();
        CFENCE();
        if (tt + 1 < NT) {
            int k0 = (tt + 1) * 32;
            stage_part<128, 32, 256, 0, 2>(Qhb + k0, AA, ldsAh[cur ^ 1], t);
            stage_part<128, 32, 256, 0, 2>(Qlb + k0, AA, ldsAl[cur ^ 1], t);
            stage_part<128, 32, 256, 0, 2>(Khb + k0, AA, ldsBh[cur ^ 1], t);
            stage_part<128, 32, 256, 0, 2>(Klb + k0, AA, ldsBl[cur ^ 1], t);
        }
        bf16x8 ah[4], al[4], bh[4], bl[4];
#pragma unroll
        for (int f = 0; f < 4; ++f) {
            ah[f] = ldsfrag<32>(ldsAh[cur], wr + f * 16, 0, lane);
            al[f] = ldsfrag<32>(ldsAl[cur], wr + f * 16, 0, lane);
            bh[f] = ldsfrag<32>(ldsBh[cur], wc + f * 16, 0, lane);
            bl[f] = ldsfrag<32>(ldsBl[cur], wc + f * 16, 0, lane);
        }
        LGKM0();
        SB0();
#pragma unroll
        for (int m = 0; m < 4; ++m)
#pragma unroll
            for (int n = 0; n < 4; ++n) {
                acc[m][n] = MFMA(ah[m], bh[n], acc[m][n]);
                acc[m][n] = MFMA(ah[m], bl[n], acc[m][n]);
                acc[m][n] = MFMA(al[m], bh[n], acc[m][n]);
            }
    }
    int r4 = (lane >> 4) << 2, cl = lane & 15;
#pragma unroll
    for (int m = 0; m < 4; ++m)
#pragma unroll
        for (int n = 0; n < 4; ++n) {
#pragma unroll
            for (int r = 0; r < 4; ++r) {
                int nrow = nrow0 + wr + m * 16 + r4 + r;
                int mcol = mcol0 + wc + n * 16 + cl;
                S[((size_t)(b * NN + nrow)) * NN + mcol] = acc[m][n][r];
            }
        }
}

// ---------- softmax: one row per WAVE (4 rows/block), shfl-only ----------
__global__ __launch_bounds__(256) void k_softmax(float* __restrict__ S,
                                                 const float* __restrict__ mask) {
    int t = threadIdx.x, lane = t & 63, wave = t >> 6;
    int row = blockIdx.x * 4 + wave;     // b*NN + n
    int b = row >> 11;
    float* srow = S + (size_t)row * NN;
    const float4* S4 = (const float4*)srow;
    const float4* M4 = (const float4*)(mask + (size_t)b * NN);
    float v[32];
#pragma unroll
    for (int i = 0; i < 8; ++i) {
        float4 s4 = S4[lane + i * 64];
        float4 m4 = M4[lane + i * 64];
        v[4 * i + 0] = s4.x + m4.x;
        v[4 * i + 1] = s4.y + m4.y;
        v[4 * i + 2] = s4.z + m4.z;
        v[4 * i + 3] = s4.w + m4.w;
    }
    float mx = v[0];
#pragma unroll
    for (int i = 1; i < 32; ++i) mx = fmaxf(mx, v[i]);
#pragma unroll
    for (int off = 32; off; off >>= 1) mx = fmaxf(mx, __shfl_xor(mx, off));
    float s = 0.f;
#pragma unroll
    for (int i = 0; i < 32; ++i) { v[i] = __expf(v[i] - mx); s += v[i]; }
#pragma unroll
    for (int off = 32; off; off >>= 1) s += __shfl_xor(s, off);
    float inv = 1.0f / s;
    ushort4* prow4 = (ushort4*)srow;     // reads of this row all done above (same wave)
#pragma unroll
    for (int i = 0; i < 8; ++i) {
        ushort4 w;
        w.x = f2bf(v[4 * i + 0] * inv);
        w.y = f2bf(v[4 * i + 1] * inv);
        w.z = f2bf(v[4 * i + 2] * inv);
        w.w = f2bf(v[4 * i + 3] * inv);
        prow4[lane + i * 64] = w;
    }
}

// ---------- PV: out[b][n][d] = sum_m P[n][m] * X[b][m][d] ----------
// 8 waves (2M x 4N, wave 64x32), BM=128 BN=128 BK=32, 3-buffer depth-2
// (VMCNT(2)), 48KB LDS -> 2 blocks/CU (grid 512). Buffer i (ushorts):
// A at i*4096 (128x32), B at 12288 + i*4096 (128x32).
__global__ __launch_bounds__(512, 4) void k_pv(const float* __restrict__ Sbuf,
                                               const unsigned short* __restrict__ XT,
                                               float* __restrict__ Out) {
    extern __shared__ unsigned short dyn[];
    int t = threadIdx.x, lane = t & 63, wave = t >> 6;
    int wm = wave >> 2, wn = wave & 3;
    // XCD swizzle of 512 blocks: 64 consecutive sbids per XCD
    int bid = blockIdx.x + 16 * (blockIdx.y + 8 * blockIdx.z);
    int sbid = (bid & 7) * 64 + (bid >> 3);
    int bx = sbid & 15;
    int by = (sbid >> 4) & 7;
    int b = sbid >> 7;
    int nrow0 = bx * 128, d0 = by * 128;
    const unsigned short* Pb = (const unsigned short*)Sbuf + (size_t)(b * NN + nrow0) * (NN * 2);
    const unsigned short* XTb = XT + (size_t)b * DD * NN + (size_t)d0 * NN;
    f32x4 acc[4][2] = {};
    // prologue: stage tiles 0 and 1 (2 issues each)
#pragma unroll
    for (int p = 0; p < 2; ++p) {
        stage_part<128, 32, 512, 0, 1>(Pb + p * 32, NN * 2, dyn + p * 4096, t);
        stage_part<128, 32, 512, 0, 1>(XTb + p * 32, NN, dyn + 12288 + p * 4096, t);
    }
    constexpr int NT = NN / 32;   // 64
    int cur = 0;
    for (int kt = 0; kt < NT; ++kt) {
        int st = (cur >= 1) ? cur - 1 : 2;          // (cur+2)%3
        CFENCE();
        if (kt == NT - 1) { VMCNT(0); } else { VMCNT(2); }  // stage(kt) drained (in-order)
        BARRIER();                 // everyone's stage(kt) landed; iter kt-1 reads done
        CFENCE();
        const unsigned short* A  = dyn + cur * 4096;
        const unsigned short* Bt = dyn + 12288 + cur * 4096;
        if (kt + 2 < NT) {
            stage_part<128, 32, 512, 0, 1>(Pb + (kt + 2) * 32, NN * 2, dyn + st * 4096, t);
            stage_part<128, 32, 512, 0, 1>(XTb + (kt + 2) * 32, NN, dyn + 12288 + st * 4096, t);
        }
        bf16x8 pa[4], vb[2];
#pragma unroll
        for (int mi = 0; mi < 4; ++mi)
            pa[mi] = ldsfrag<32>(A, wm * 64 + mi * 16, 0, lane);
#pragma unroll
        for (int ni = 0; ni < 2; ++ni)
            vb[ni] = ldsfrag<32>(Bt, wn * 32 + ni * 16, 0, lane);
        LGKM0();
        SB0();
#pragma unroll
        for (int mi = 0; mi < 4; ++mi)
#pragma unroll
            for (int ni = 0; ni < 2; ++ni)
                acc[mi][ni] = MFMA(pa[mi], vb[ni], acc[mi][ni]);
        cur = (cur == 2) ? 0 : cur + 1;
    }
    int r4 = (lane >> 4) << 2, cl = lane & 15;
#pragma unroll
    for (int mi = 0; mi < 4; ++mi)
#pragma unroll
        for (int ni = 0; ni < 2; ++ni) {
#pragma unroll
            for (int r = 0; r < 4; ++r) {
                int row = b * NN + nrow0 + wm * 64 + mi * 16 + r4 + r;
                int dc = d0 + wn * 32 + ni * 16 + cl;
                Out[(size_t)row * DD + dc] = acc[mi][ni][r];
            }
        }
}

extern "C" void kernel_launch(void* const* d_in, const int* in_sizes, int n_in,
                              void* d_out, int out_size, void* d_ws, size_t ws_size,
                              hipStream_t stream) {
    const float* X    = (const float*)d_in[0];
    const float* mask = (const float*)d_in[1];
    const float* Wq   = (const float*)d_in[2];
    const float* bq   = (const float*)d_in[3];
    const float* Wk   = (const float*)d_in[4];
    const float* bk   = (const float*)d_in[5];
    float* Out = (float*)d_out;

    unsigned short* Xh   = (unsigned short*)d_ws;
    unsigned short* Xl   = Xh + (size_t)BB * NN * DD;
    unsigned short* XT   = Xl + (size_t)BB * NN * DD;
    unsigned short* WqTh = XT + (size_t)BB * NN * DD;
    unsigned short* WqTl = WqTh + (size_t)AA * DD;
    unsigned short* WkTh = WqTl + (size_t)AA * DD;
    unsigned short* WkTl = WkTh + (size_t)AA * DD;
    unsigned short* Qh   = WkTl + (size_t)AA * DD;
    unsigned short* Ql   = Qh + (size_t)BB * NN * AA;
    unsigned short* Kh   = Ql + (size_t)BB * NN * AA;
    unsigned short* Kl   = Kh + (size_t)BB * NN * AA;
    float* S = (float*)(Kl + (size_t)BB * NN * AA);

    hipFuncSetAttribute((const void*)k_pv,
                        hipFuncAttributeMaxDynamicSharedMemorySize, 49152);
    hipFuncSetAttribute((const void*)k_proj,
                        hipFuncAttributeMaxDynamicSharedMemorySize, 73728);

    k_prep<<<dim3(NN / 64, DD / 64, BB), 256, 0, stream>>>(X, Xh, Xl, XT);
    k_wsplit<<<dim3((AA * DD) / 256), 256, 0, stream>>>(Wq, WqTh, WqTl);
    k_wsplit<<<dim3((AA * DD) / 256), 256, 0, stream>>>(Wk, WkTh, WkTl);

    k_proj<<<dim3((BB * NN) / 64 * 4), 256, 73728, stream>>>(Xh, Xl, WqTh, WqTl, WkTh, WkTl,
                                                             bq, bk, Qh, Ql, Kh, Kl);

    k_scores<<<dim3(NN / 128, NN / 128, BB), 256, 0, stream>>>(Qh, Ql, Kh, Kl, S);
    k_softmax<<<dim3(BB * NN / 4), 256, 0, stream>>>(S, mask);
    k_pv<<<dim3(16, 8, BB), 512, 49152, stream>>>(S, XT, Out);
}

// Round 17
// 145.013 us; speedup vs baseline: 1.0640x; 1.0640x over previous
//
#include <hip/hip_runtime.h>
#include <hip/hip_bf16.h>

// GlobalAttention: B=4, N=2048, D=1024, A=256, f32 in/out.
// out = softmax( (X Wq + bq)(X Wk + bk)^T + mask ) X
// R17 = R10-exact (best measured, 146.4us) + fused wsplit (one launch).
// Structure: split-bf16 (hi+lo) x3 MFMA for proj+scores (precision), bf16 PV.
// All GEMMs: gload_lds staging w/ both-sides XOR slot swizzle, sound pipeline
// { VMCNT(N); BARRIER; stage(next); ds_read; lgkm drain; setprio MFMA }.
// proj: 64x128 tile, 3-buf depth-2 VMCNT(6), XCD-grouped (X shared per XCD).
// pv: 128x256 tile, 8 waves, 3-buf depth-2 VMCNT(6). scores: 128x128 2-buf.
// Pinned at the 2-barrier 128-tile structural rate (~850 TF) after 7-variant
// ablation; 8-phase/256-tile escapes don't fit this grid (m232-consistent).

#define BB 4
#define NN 2048
#define DD 1024
#define AA 256

using bf16x8 = __attribute__((ext_vector_type(8))) __bf16;
using f32x4  = __attribute__((ext_vector_type(4))) float;

#define MFMA(a, b, c) __builtin_amdgcn_mfma_f32_16x16x32_bf16(a, b, c, 0, 0, 0)

#define VMCNT(n) asm volatile("s_waitcnt vmcnt(" #n ")" ::: "memory")
#define LGKM0()  asm volatile("s_waitcnt lgkmcnt(0)" ::: "memory")
#define SB0()    __builtin_amdgcn_sched_barrier(0)
#define CFENCE() asm volatile("" ::: "memory")
#define BARRIER() __builtin_amdgcn_s_barrier()

static __device__ __forceinline__ unsigned short f2bf(float x) {
    union { float f; unsigned int u; } c; c.f = x;
    unsigned int u = c.u;
    u += 0x7fffu + ((u >> 16) & 1u);   // round-to-nearest-even
    return (unsigned short)(u >> 16);
}
static __device__ __forceinline__ float bf2f(unsigned short h) {
    union { unsigned int u; float f; } c; c.u = ((unsigned int)h) << 16;
    return c.f;
}

// ---- swizzle: slot' = slot ^ swz(row); involution on stage-src AND ds_read ----
template<int SLOTS>
static __device__ __forceinline__ int swz(int r) {
    return (SLOTS == 4) ? ((r >> 1) & 3) : (r & 7);
}

template<int ROWS, int BK, int THREADS, int I0, int I1>
static __device__ __forceinline__ void stage_part(const unsigned short* __restrict__ g,
                                                  int pitch, unsigned short* lds, int t) {
    constexpr int SLOTS = BK / 8;
#pragma unroll
    for (int i = I0; i < I1; ++i) {
        int tt = t + i * THREADS;
        int row = tt / SLOTS;
        int slot = (tt % SLOTS) ^ swz<SLOTS>(row);
        const char* src = (const char*)(g + (size_t)row * pitch) + slot * 16;
        __builtin_amdgcn_global_load_lds((const unsigned int*)src,
                                         (unsigned int*)((char*)lds + (size_t)tt * 16),
                                         16, 0, 0);
    }
}

template<int BK>
static __device__ __forceinline__ bf16x8 ldsfrag(const unsigned short* lds, int row,
                                                 int ks, int lane) {
    constexpr int SLOTS = BK / 8;
    int r = row + (lane & 15);
    int slot = (ks * 4 + (lane >> 4)) ^ swz<SLOTS>(r);
    return *reinterpret_cast<const bf16x8*>((const char*)lds + (size_t)r * (BK * 2) + slot * 16);
}

// ---------- fused prep: X -> Xh, Xl (row-major) and XT bf16 [B][D][N] ----------
__global__ __launch_bounds__(256) void k_prep(const float* __restrict__ X,
                                              unsigned short* __restrict__ Xh,
                                              unsigned short* __restrict__ Xl,
                                              unsigned short* __restrict__ XT) {
    __shared__ unsigned short tile[64][65];   // [d][n], hi values
    int t = threadIdx.x;
    int n0 = blockIdx.x * 64, d0 = blockIdx.y * 64;
    const float* Xb = X + (size_t)blockIdx.z * NN * DD;
    unsigned short* Xhb = Xh + (size_t)blockIdx.z * NN * DD;
    unsigned short* Xlb = Xl + (size_t)blockIdx.z * NN * DD;
    unsigned short* XTb = XT + (size_t)blockIdx.z * DD * NN;
    int r = t >> 4, c4 = (t & 15) * 4;
#pragma unroll
    for (int i = 0; i < 4; ++i) {
        int row = r + 16 * i;
        float4 v = *reinterpret_cast<const float4*>(Xb + (size_t)(n0 + row) * DD + d0 + c4);
        ushort4 h, l;
        h.x = f2bf(v.x); l.x = f2bf(v.x - bf2f(h.x));
        h.y = f2bf(v.y); l.y = f2bf(v.y - bf2f(h.y));
        h.z = f2bf(v.z); l.z = f2bf(v.z - bf2f(h.z));
        h.w = f2bf(v.w); l.w = f2bf(v.w - bf2f(h.w));
        *reinterpret_cast<ushort4*>(Xhb + (size_t)(n0 + row) * DD + d0 + c4) = h;
        *reinterpret_cast<ushort4*>(Xlb + (size_t)(n0 + row) * DD + d0 + c4) = l;
        tile[c4 + 0][row] = h.x;
        tile[c4 + 1][row] = h.y;
        tile[c4 + 2][row] = h.z;
        tile[c4 + 3][row] = h.w;
    }
    __syncthreads();
    int j = t & 63, i4 = t >> 6;
#pragma unroll
    for (int jj = i4; jj < 64; jj += 4)
        XTb[(size_t)(d0 + jj) * NN + n0 + j] = tile[jj][j];
}

// ---------- prep: W[D][A] -> WT hi/lo bf16 [A][D]; grid.y selects Wq/Wk ----------
__global__ __launch_bounds__(256) void k_wsplit(const float* __restrict__ Wq,
                                                const float* __restrict__ Wk,
                                                unsigned short* __restrict__ WqTh,
                                                unsigned short* __restrict__ WqTl,
                                                unsigned short* __restrict__ WkTh,
                                                unsigned short* __restrict__ WkTl) {
    const float* W = blockIdx.y ? Wk : Wq;
    unsigned short* WTh = blockIdx.y ? WkTh : WqTh;
    unsigned short* WTl = blockIdx.y ? WkTl : WqTl;
    int idx = blockIdx.x * 256 + threadIdx.x;
    int a = idx >> 10;
    int d = idx & (DD - 1);
    float w = W[(size_t)d * AA + a];
    unsigned short hi = f2bf(w);
    WTh[idx] = hi;
    WTl[idx] = f2bf(w - bf2f(hi));
}

// ---------- fused proj: {Q,K} = X W{q,k} + b -> split bf16 [B*N][A] ----------
// 64x128 tile, 4 waves of 64x32, 3-buffer depth-2 (VMCNT(6)). grid (512).
__global__ __launch_bounds__(256) void k_proj(const unsigned short* __restrict__ Xh,
                                              const unsigned short* __restrict__ Xl,
                                              const unsigned short* __restrict__ WqTh,
                                              const unsigned short* __restrict__ WqTl,
                                              const unsigned short* __restrict__ WkTh,
                                              const unsigned short* __restrict__ WkTl,
                                              const float* __restrict__ bq,
                                              const float* __restrict__ bk,
                                              unsigned short* __restrict__ Qh,
                                              unsigned short* __restrict__ Ql,
                                              unsigned short* __restrict__ Kh,
                                              unsigned short* __restrict__ Kl) {
    extern __shared__ unsigned short dyn[];
    int t = threadIdx.x, lane = t & 63, wave = t >> 6;
    int bid = blockIdx.x;
    int xcd = bid & 7, idx = bid >> 3;        // idx 0..63
    int rowpanel = xcd * 16 + (idx >> 2);
    int yy = idx & 3;
    int row0 = rowpanel * 64;
    int which = yy >> 1;
    int col0 = (yy & 1) * 128;
    const unsigned short* BTh = which ? WkTh : WqTh;
    const unsigned short* BTl = which ? WkTl : WqTl;
    const float* bias = which ? bk : bq;
    unsigned short* Oh = which ? Kh : Qh;
    unsigned short* Ol = which ? Kl : Ql;
    const unsigned short* Abase_h = Xh + (size_t)row0 * DD;
    const unsigned short* Abase_l = Xl + (size_t)row0 * DD;
    const unsigned short* Bbase_h = BTh + (size_t)col0 * DD;
    const unsigned short* Bbase_l = BTl + (size_t)col0 * DD;
    int wc = wave * 32;
    f32x4 acc[4][2] = {};
#pragma unroll
    for (int p = 0; p < 2; ++p) {
        unsigned short* bp = dyn + p * 12288;
        int k0 = p * 32;
        stage_part<64, 32, 256, 0, 1>(Abase_h + k0, DD, bp, t);
        stage_part<64, 32, 256, 0, 1>(Abase_l + k0, DD, bp + 2048, t);
        stage_part<128, 32, 256, 0, 2>(Bbase_h + k0, DD, bp + 4096, t);
        stage_part<128, 32, 256, 0, 2>(Bbase_l + k0, DD, bp + 8192, t);
    }
    constexpr int NT = DD / 32;   // 32
    int cur = 0;
    for (int tt = 0; tt < NT; ++tt) {
        int st = (cur >= 1) ? cur - 1 : 2;          // (cur+2)%3
        CFENCE();
        if (tt == NT - 1) { VMCNT(0); } else { VMCNT(6); }
        BARRIER();
        CFENCE();
        unsigned short* bc = dyn + cur * 12288;
        if (tt + 2 < NT) {
            unsigned short* bs = dyn + st * 12288;
            int k0 = (tt + 2) * 32;
            stage_part<64, 32, 256, 0, 1>(Abase_h + k0, DD, bs, t);
            stage_part<64, 32, 256, 0, 1>(Abase_l + k0, DD, bs + 2048, t);
            stage_part<128, 32, 256, 0, 2>(Bbase_h + k0, DD, bs + 4096, t);
            stage_part<128, 32, 256, 0, 2>(Bbase_l + k0, DD, bs + 8192, t);
        }
        bf16x8 ah[4], al[4], bh[2], bl[2];
#pragma unroll
        for (int f = 0; f < 4; ++f) {
            ah[f] = ldsfrag<32>(bc, f * 16, 0, lane);
            al[f] = ldsfrag<32>(bc + 2048, f * 16, 0, lane);
        }
#pragma unroll
        for (int n = 0; n < 2; ++n) {
            bh[n] = ldsfrag<32>(bc + 4096, wc + n * 16, 0, lane);
            bl[n] = ldsfrag<32>(bc + 8192, wc + n * 16, 0, lane);
        }
        LGKM0();
        SB0();
        __builtin_amdgcn_s_setprio(1);
#pragma unroll
        for (int m = 0; m < 4; ++m)
#pragma unroll
            for (int n = 0; n < 2; ++n) {
                acc[m][n] = MFMA(ah[m], bh[n], acc[m][n]);
                acc[m][n] = MFMA(ah[m], bl[n], acc[m][n]);
                acc[m][n] = MFMA(al[m], bh[n], acc[m][n]);
            }
        __builtin_amdgcn_s_setprio(0);
        cur = (cur == 2) ? 0 : cur + 1;
    }
    int r4 = (lane >> 4) << 2, cl = lane & 15;
#pragma unroll
    for (int m = 0; m < 4; ++m)
#pragma unroll
        for (int n = 0; n < 2; ++n) {
            int col = col0 + wc + n * 16 + cl;
            float bv = bias[col];
#pragma unroll
            for (int r = 0; r < 4; ++r) {
                int row = row0 + m * 16 + r4 + r;
                float v = acc[m][n][r] + bv;
                unsigned short hi = f2bf(v);
                size_t o = (size_t)row * AA + col;
                Oh[o] = hi;
                Ol[o] = f2bf(v - bf2f(hi));
            }
        }
}

// ---------- scores: S[b][n][m] = sum_a Q[n][a] K[m][a]  (f32) ----------
__global__ __launch_bounds__(256) void k_scores(const unsigned short* __restrict__ Qh,
                                                const unsigned short* __restrict__ Ql,
                                                const unsigned short* __restrict__ Kh,
                                                const unsigned short* __restrict__ Kl,
                                                float* __restrict__ S) {
    __shared__ unsigned short ldsAh[2][128 * 32], ldsAl[2][128 * 32];
    __shared__ unsigned short ldsBh[2][128 * 32], ldsBl[2][128 * 32];
    int t = threadIdx.x, lane = t & 63, wave = t >> 6;
    int bid = blockIdx.x + 16 * blockIdx.y + 256 * blockIdx.z;
    int sbid = (bid & 7) * 128 + (bid >> 3);
    int b = sbid >> 8;
    int nrow0 = (sbid & 15) * 128;
    int mcol0 = ((sbid >> 4) & 15) * 128;
    const unsigned short* Qhb = Qh + (size_t)(b * NN + nrow0) * AA;
    const unsigned short* Qlb = Ql + (size_t)(b * NN + nrow0) * AA;
    const unsigned short* Khb = Kh + (size_t)(b * NN + mcol0) * AA;
    const unsigned short* Klb = Kl + (size_t)(b * NN + mcol0) * AA;
    int wr = (wave >> 1) * 64, wc = (wave & 1) * 64;
    f32x4 acc[4][4] = {};
    stage_part<128, 32, 256, 0, 2>(Qhb, AA, ldsAh[0], t);
    stage_part<128, 32, 256, 0, 2>(Qlb, AA, ldsAl[0], t);
    stage_part<128, 32, 256, 0, 2>(Khb, AA, ldsBh[0], t);
    stage_part<128, 32, 256, 0, 2>(Klb, AA, ldsBl[0], t);
    constexpr int NT = AA / 32;
    for (int tt = 0; tt < NT; ++tt) {
        int cur = tt & 1;
        CFENCE();
        VMCNT(0);
        BARRIER();
        CFENCE();
        if (tt + 1 < NT) {
            int k0 = (tt + 1) * 32;
            stage_part<128, 32, 256, 0, 2>(Qhb + k0, AA, ldsAh[cur ^ 1], t);
            stage_part<128, 32, 256, 0, 2>(Qlb + k0, AA, ldsAl[cur ^ 1], t);
            stage_part<128, 32, 256, 0, 2>(Khb + k0, AA, ldsBh[cur ^ 1], t);
            stage_part<128, 32, 256, 0, 2>(Klb + k0, AA, ldsBl[cur ^ 1], t);
        }
        bf16x8 ah[4], al[4], bh[4], bl[4];
#pragma unroll
        for (int f = 0; f < 4; ++f) {
            ah[f] = ldsfrag<32>(ldsAh[cur], wr + f * 16, 0, lane);
            al[f] = ldsfrag<32>(ldsAl[cur], wr + f * 16, 0, lane);
            bh[f] = ldsfrag<32>(ldsBh[cur], wc + f * 16, 0, lane);
            bl[f] = ldsfrag<32>(ldsBl[cur], wc + f * 16, 0, lane);
        }
        LGKM0();
        SB0();
        __builtin_amdgcn_s_setprio(1);
#pragma unroll
        for (int m = 0; m < 4; ++m)
#pragma unroll
            for (int n = 0; n < 4; ++n) {
                acc[m][n] = MFMA(ah[m], bh[n], acc[m][n]);
                acc[m][n] = MFMA(ah[m], bl[n], acc[m][n]);
                acc[m][n] = MFMA(al[m], bh[n], acc[m][n]);
            }
        __builtin_amdgcn_s_setprio(0);
    }
    int r4 = (lane >> 4) << 2, cl = lane & 15;
#pragma unroll
    for (int m = 0; m < 4; ++m)
#pragma unroll
        for (int n = 0; n < 4; ++n) {
#pragma unroll
            for (int r = 0; r < 4; ++r) {
                int nrow = nrow0 + wr + m * 16 + r4 + r;
                int mcol = mcol0 + wc + n * 16 + cl;
                S[((size_t)(b * NN + nrow)) * NN + mcol] = acc[m][n][r];
            }
        }
}

// ---------- softmax: one row per WAVE (4 rows/block), shfl-only ----------
__global__ __launch_bounds__(256) void k_softmax(float* __restrict__ S,
                                                 const float* __restrict__ mask) {
    int t = threadIdx.x, lane = t & 63, wave = t >> 6;
    int row = blockIdx.x * 4 + wave;     // b*NN + n
    int b = row >> 11;
    float* srow = S + (size_t)row * NN;
    const float4* S4 = (const float4*)srow;
    const float4* M4 = (const float4*)(mask + (size_t)b * NN);
    float v[32];
#pragma unroll
    for (int i = 0; i < 8; ++i) {
        float4 s4 = S4[lane + i * 64];
        float4 m4 = M4[lane + i * 64];
        v[4 * i + 0] = s4.x + m4.x;
        v[4 * i + 1] = s4.y + m4.y;
        v[4 * i + 2] = s4.z + m4.z;
        v[4 * i + 3] = s4.w + m4.w;
    }
    float mx = v[0];
#pragma unroll
    for (int i = 1; i < 32; ++i) mx = fmaxf(mx, v[i]);
#pragma unroll
    for (int off = 32; off; off >>= 1) mx = fmaxf(mx, __shfl_xor(mx, off));
    float s = 0.f;
#pragma unroll
    for (int i = 0; i < 32; ++i) { v[i] = __expf(v[i] - mx); s += v[i]; }
#pragma unroll
    for (int off = 32; off; off >>= 1) s += __shfl_xor(s, off);
    float inv = 1.0f / s;
    ushort4* prow4 = (ushort4*)srow;     // reads of this row all done above (same wave)
#pragma unroll
    for (int i = 0; i < 8; ++i) {
        ushort4 w;
        w.x = f2bf(v[4 * i + 0] * inv);
        w.y = f2bf(v[4 * i + 1] * inv);
        w.z = f2bf(v[4 * i + 2] * inv);
        w.w = f2bf(v[4 * i + 3] * inv);
        prow4[lane + i * 64] = w;
    }
}

// ---------- PV: out[b][n][d] = sum_m P[n][m] * X[b][m][d] ----------
// 8 waves (2M x 4N, wave 64x64), BM=128 BN=256 BK=64, 3-buffer depth-2,
// sound order: VMCNT(6) -> BARRIER -> stage(kt+2) -> read-once -> MFMA.
__global__ __launch_bounds__(512, 2) void k_pv(const float* __restrict__ Sbuf,
                                               const unsigned short* __restrict__ XT,
                                               float* __restrict__ Out) {
    extern __shared__ unsigned short dyn[];
    int t = threadIdx.x, lane = t & 63, wave = t >> 6;
    int wm = wave >> 2, wn = wave & 3;
    int bid = blockIdx.x + 16 * (blockIdx.y + 4 * blockIdx.z);
    int sbid = (bid & 7) * 32 + (bid >> 3);
    int bx = sbid & 15;
    int by = (sbid >> 4) & 3;
    int b = sbid >> 6;
    int nrow0 = bx * 128, d0 = by * 256;
    const unsigned short* Pb = (const unsigned short*)Sbuf + (size_t)(b * NN + nrow0) * (NN * 2);
    const unsigned short* XTb = XT + (size_t)b * DD * NN + (size_t)d0 * NN;
    f32x4 acc[4][4] = {};
    stage_part<128, 64, 512, 0, 2>(Pb, NN * 2, dyn, t);
    stage_part<256, 64, 512, 0, 4>(XTb, NN, dyn + 24576, t);
    stage_part<128, 64, 512, 0, 2>(Pb + 64, NN * 2, dyn + 8192, t);
    stage_part<256, 64, 512, 0, 4>(XTb + 64, NN, dyn + 24576 + 16384, t);
    constexpr int NT = NN / 64;   // 32
    int cur = 0;
    for (int kt = 0; kt < NT; ++kt) {
        int st = (cur >= 1) ? cur - 1 : 2;          // (cur+2)%3
        CFENCE();
        if (kt == NT - 1) { VMCNT(0); } else { VMCNT(6); }  // stage(kt) drained (in-order)
        BARRIER();                 // everyone's stage(kt) landed; iter kt-1 reads done
        CFENCE();
        const unsigned short* A  = dyn + cur * 8192;
        const unsigned short* Bt = dyn + 24576 + cur * 16384;
        if (kt + 2 < NT) {
            stage_part<128, 64, 512, 0, 2>(Pb + (kt + 2) * 64, NN * 2, dyn + st * 8192, t);
            stage_part<256, 64, 512, 0, 4>(XTb + (kt + 2) * 64, NN, dyn + 24576 + st * 16384, t);
        }
        bf16x8 pa[4][2], vb[4][2];
#pragma unroll
        for (int mi = 0; mi < 4; ++mi)
#pragma unroll
            for (int ks = 0; ks < 2; ++ks)
                pa[mi][ks] = ldsfrag<64>(A, wm * 64 + mi * 16, ks, lane);
#pragma unroll
        for (int ni = 0; ni < 4; ++ni)
#pragma unroll
            for (int ks = 0; ks < 2; ++ks)
                vb[ni][ks] = ldsfrag<64>(Bt, wn * 64 + ni * 16, ks, lane);
        LGKM0();
        SB0();
        __builtin_amdgcn_s_setprio(1);
#pragma unroll
        for (int ks = 0; ks < 2; ++ks)
#pragma unroll
            for (int mi = 0; mi < 4; ++mi)
#pragma unroll
                for (int ni = 0; ni < 4; ++ni)
                    acc[mi][ni] = MFMA(pa[mi][ks], vb[ni][ks], acc[mi][ni]);
        __builtin_amdgcn_s_setprio(0);
        cur = (cur == 2) ? 0 : cur + 1;
    }
    int r4 = (lane >> 4) << 2, cl = lane & 15;
#pragma unroll
    for (int mi = 0; mi < 4; ++mi)
#pragma unroll
        for (int ni = 0; ni < 4; ++ni) {
#pragma unroll
            for (int r = 0; r < 4; ++r) {
                int row = b * NN + nrow0 + wm * 64 + mi * 16 + r4 + r;
                int dc = d0 + wn * 64 + ni * 16 + cl;
                Out[(size_t)row * DD + dc] = acc[mi][ni][r];
            }
        }
}

extern "C" void kernel_launch(void* const* d_in, const int* in_sizes, int n_in,
                              void* d_out, int out_size, void* d_ws, size_t ws_size,
                              hipStream_t stream) {
    const float* X    = (const float*)d_in[0];
    const float* mask = (const float*)d_in[1];
    const float* Wq   = (const float*)d_in[2];
    const float* bq   = (const float*)d_in[3];
    const float* Wk   = (const float*)d_in[4];
    const float* bk   = (const float*)d_in[5];
    float* Out = (float*)d_out;

    unsigned short* Xh   = (unsigned short*)d_ws;
    unsigned short* Xl   = Xh + (size_t)BB * NN * DD;
    unsigned short* XT   = Xl + (size_t)BB * NN * DD;
    unsigned short* WqTh = XT + (size_t)BB * NN * DD;
    unsigned short* WqTl = WqTh + (size_t)AA * DD;
    unsigned short* WkTh = WqTl + (size_t)AA * DD;
    unsigned short* WkTl = WkTh + (size_t)AA * DD;
    unsigned short* Qh   = WkTl + (size_t)AA * DD;
    unsigned short* Ql   = Qh + (size_t)BB * NN * AA;
    unsigned short* Kh   = Ql + (size_t)BB * NN * AA;
    unsigned short* Kl   = Kh + (size_t)BB * NN * AA;
    float* S = (float*)(Kl + (size_t)BB * NN * AA);

    hipFuncSetAttribute((const void*)k_pv,
                        hipFuncAttributeMaxDynamicSharedMemorySize, 147456);
    hipFuncSetAttribute((const void*)k_proj,
                        hipFuncAttributeMaxDynamicSharedMemorySize, 73728);

    k_prep<<<dim3(NN / 64, DD / 64, BB), 256, 0, stream>>>(X, Xh, Xl, XT);
    k_wsplit<<<dim3((AA * DD) / 256, 2), 256, 0, stream>>>(Wq, Wk, WqTh, WqTl, WkTh, WkTl);

    k_proj<<<dim3((BB * NN) / 64 * 4), 256, 73728, stream>>>(Xh, Xl, WqTh, WqTl, WkTh, WkTl,
                                                             bq, bk, Qh, Ql, Kh, Kl);

    k_scores<<<dim3(NN / 128, NN / 128, BB), 256, 0, stream>>>(Qh, Ql, Kh, Kl, S);
    k_softmax<<<dim3(BB * NN / 4), 256, 0, stream>>>(S, mask);
    k_pv<<<dim3(16, 4, BB), 512, 147456, stream>>>(S, XT, Out);
}